// Round 1
// baseline (1595.396 us; speedup 1.0000x reference)
//
#include <hip/hip_runtime.h>

#define SEQ 2036
#define BB 32
#define NFEAT 64
#define NCITY 100
#define DDIM 512
#define NOUT 4
#define LHIST 2048

__device__ __forceinline__ float leaky_f(float x) { return x > 0.f ? x : 0.2f * x; }

// ---- weight transpose: w[Dout][K3] -> wT[K3][Dout] ----
__global__ void transpose_w_kernel(const float* __restrict__ w, float* __restrict__ wT,
                                   int Dout, int K3) {
    int i = blockIdx.x * blockDim.x + threadIdx.x;
    if (i < Dout * K3) {
        int d = i / K3, k = i - d * K3;
        wT[k * Dout + d] = w[i];
    }
}

// ---- city embed: c[b][d] = static[b]·W_city[d] + b_city[d] ----
__global__ void city_kernel(const float* __restrict__ st, const float* __restrict__ Wc,
                            const float* __restrict__ bc, float* __restrict__ c) {
    int b = blockIdx.x, d = threadIdx.x;
    const float* sb = st + b * NCITY;
    float acc = bc[d];
#pragma unroll 4
    for (int f = 0; f < NCITY; ++f) acc = fmaf(sb[f], Wc[d * NCITY + f], acc);
    c[b * DDIM + d] = acc;
}

// ---- fused conv1d(K=3,VALID) + bias + leaky + maxpool3(VALID) ----
// in: [B][CIN][Lin], wT: [CIN*3][DOUT], out: [B][DOUT][Lpool] or (TR) [S][B][DOUT]
// Lpool = Lin - 4. One thread per dout, one block per (s-tile, b).
template <int CIN, int DOUT, int TILE, bool TR>
__global__ void conv_pool_kernel(const float* __restrict__ in, const float* __restrict__ wT,
                                 const float* __restrict__ bias, float* __restrict__ out,
                                 int Lin) {
    const int Lpool = Lin - 4;
    const int b = blockIdx.y;
    const int s0 = blockIdx.x * TILE;
    const int d = threadIdx.x;
    __shared__ float tile[CIN][TILE + 4];
    const float* inb = in + (size_t)b * CIN * Lin;
    for (int idx = threadIdx.x; idx < CIN * (TILE + 4); idx += DOUT) {
        int cin = idx / (TILE + 4), p = idx - cin * (TILE + 4);
        int s = s0 + p;
        tile[cin][p] = (s < Lin) ? inb[(size_t)cin * Lin + s] : 0.f;
    }
    __syncthreads();
    float acc[TILE + 2];
#pragma unroll
    for (int p = 0; p < TILE + 2; ++p) acc[p] = 0.f;
    for (int cin = 0; cin < CIN; ++cin) {
        float w0 = wT[(cin * 3 + 0) * DOUT + d];
        float w1 = wT[(cin * 3 + 1) * DOUT + d];
        float w2 = wT[(cin * 3 + 2) * DOUT + d];
        float r0 = tile[cin][0], r1 = tile[cin][1];
#pragma unroll
        for (int p = 0; p < TILE + 2; ++p) {
            float r2 = tile[cin][p + 2];
            acc[p] = fmaf(r0, w0, fmaf(r1, w1, fmaf(r2, w2, acc[p])));
            r0 = r1; r1 = r2;
        }
    }
    float bv = bias[d];
#pragma unroll
    for (int i = 0; i < TILE; ++i) {
        int sp = s0 + i;
        if (sp < Lpool) {
            float m = fmaxf(fmaxf(acc[i], acc[i + 1]), acc[i + 2]) + bv;
            float y = leaky_f(m);
            if (TR) out[((size_t)sp * BB + b) * DOUT + d] = y;
            else    out[((size_t)b * DOUT + d) * Lpool + sp] = y;
        }
    }
}

// ---- fused epilogue: embed GEMM + leaky + add h3 + LN1 + city scale + LN2 ----
// Rows = S*B (row r -> s = r/32, b = r%32). 16 rows per block, 256 threads.
__global__ __launch_bounds__(256) void epilogue_kernel(
    const float* __restrict__ input,   // [S*B][64]
    const float* __restrict__ Wf,      // [512][64]
    const float* __restrict__ bf,      // [512]
    const float* __restrict__ h3,      // [S*B][512]
    const float* __restrict__ cvec,    // [B][512]
    const float* __restrict__ g1, const float* __restrict__ be1,
    const float* __restrict__ g2, const float* __restrict__ be2,
    float* __restrict__ outp)          // [S*B][512]
{
    __shared__ float in_lds[16 * 64];
    __shared__ float W_lds[64 * 65];     // +1 pad: stride 65 -> conflict-free
    __shared__ float x_lds[16 * 512];
    const int t = threadIdx.x;
    const long r0 = (long)blockIdx.x * 16;

    for (int idx = t; idx < 16 * 64; idx += 256) in_lds[idx] = input[r0 * 64 + idx];

    for (int chunk = 0; chunk < 8; ++chunk) {
        __syncthreads();  // in_lds ready (chunk 0); previous chunk done with W_lds
        for (int idx = t; idx < 64 * 64; idx += 256) {
            int dl = idx >> 6, f = idx & 63;
            W_lds[dl * 65 + f] = Wf[(chunk * 64 + dl) * 64 + f];
        }
        __syncthreads();
#pragma unroll
        for (int i = 0; i < 4; ++i) {
            int o = t + 256 * i;
            int row = o >> 6, dl = o & 63;
            int d = chunk * 64 + dl;
            float acc = bf[d];
            const float* inr = &in_lds[row * 64];
            const float* wr = &W_lds[dl * 65];
#pragma unroll
            for (int f = 0; f < 64; ++f) acc = fmaf(inr[f], wr[f], acc);
            float x = leaky_f(acc);
            x += h3[(r0 + row) * 512 + d];
            x_lds[row * 512 + d] = x;
        }
    }
    __syncthreads();

    const int wave = t >> 6, lane = t & 63;
    float g1r[8], b1r[8], g2r[8], b2r[8];
#pragma unroll
    for (int j = 0; j < 8; ++j) {
        int d = lane + 64 * j;
        g1r[j] = g1[d]; b1r[j] = be1[d]; g2r[j] = g2[d]; b2r[j] = be2[d];
    }
    for (int rr = 0; rr < 4; ++rr) {
        int row = wave * 4 + rr;
        long r = r0 + row;
        int b = (int)(r & 31);
        float v[8];
        float s = 0.f;
#pragma unroll
        for (int j = 0; j < 8; ++j) { v[j] = x_lds[row * 512 + lane + 64 * j]; s += v[j]; }
#pragma unroll
        for (int off = 32; off; off >>= 1) s += __shfl_xor(s, off);
        float m = s * (1.f / 512.f);
        float vs = 0.f;
#pragma unroll
        for (int j = 0; j < 8; ++j) { float dd = v[j] - m; vs += dd * dd; }
#pragma unroll
        for (int off = 32; off; off >>= 1) vs += __shfl_xor(vs, off);
        float rstd = rsqrtf(vs * (1.f / 512.f) + 1e-5f);
        float z[8]; float s2 = 0.f;
#pragma unroll
        for (int j = 0; j < 8; ++j) {
            int d = lane + 64 * j;
            float y = (v[j] - m) * rstd * g1r[j] + b1r[j];
            z[j] = y * cvec[b * 512 + d];
            s2 += z[j];
        }
#pragma unroll
        for (int off = 32; off; off >>= 1) s2 += __shfl_xor(s2, off);
        float m2 = s2 * (1.f / 512.f);
        float vs2 = 0.f;
#pragma unroll
        for (int j = 0; j < 8; ++j) { float dd = z[j] - m2; vs2 += dd * dd; }
#pragma unroll
        for (int off = 32; off; off >>= 1) vs2 += __shfl_xor(vs2, off);
        float rstd2 = rsqrtf(vs2 * (1.f / 512.f) + 1e-5f);
#pragma unroll
        for (int j = 0; j < 8; ++j) {
            int d = lane + 64 * j;
            outp[r * 512 + d] = (z[j] - m2) * rstd2 * g2r[j] + b2r[j];
        }
    }
}

extern "C" void kernel_launch(void* const* d_in, const int* in_sizes, int n_in,
                              void* d_out, int out_size, void* d_ws, size_t ws_size,
                              hipStream_t stream) {
    const float* input  = (const float*)d_in[0];   // [2036][32][64]
    const float* history= (const float*)d_in[1];   // [32][4][2048]
    const float* stat   = (const float*)d_in[2];   // [32][100]
    const float* W_feat = (const float*)d_in[3];   // [512][64]
    const float* b_feat = (const float*)d_in[4];
    const float* w1     = (const float*)d_in[5];   // [128][4][3]
    const float* b1     = (const float*)d_in[6];
    const float* w2     = (const float*)d_in[7];   // [256][128][3]
    const float* b2     = (const float*)d_in[8];
    const float* w3     = (const float*)d_in[9];   // [512][256][3]
    const float* b3     = (const float*)d_in[10];
    const float* g1     = (const float*)d_in[11];
    const float* beta1  = (const float*)d_in[12];
    const float* W_city = (const float*)d_in[13];  // [512][100]
    const float* b_city = (const float*)d_in[14];
    const float* g2     = (const float*)d_in[15];
    const float* beta2  = (const float*)d_in[16];
    float* out = (float*)d_out;

    // workspace layout (floats), all offsets multiples of 64
    float* ws = (float*)d_ws;
    size_t off = 0;
    float* h1  = ws + off; off += (size_t)BB * 128 * 2044;   // 8,372,224
    float* h2  = ws + off; off += (size_t)BB * 256 * 2040;   // 16,711,680
    float* h3  = ws + off; off += (size_t)SEQ * BB * 512;    // 33,357,824
    float* cv  = ws + off; off += (size_t)BB * DDIM;         // 16,384
    float* w1T = ws + off; off += 128 * 4 * 3;               // 1,536
    float* w2T = ws + off; off += 256 * 128 * 3;             // 98,304
    float* w3T = ws + off; off += 512 * 256 * 3;             // 393,216

    // weight transposes
    transpose_w_kernel<<<(128 * 12 + 255) / 256, 256, 0, stream>>>(w1, w1T, 128, 12);
    transpose_w_kernel<<<(256 * 384 + 255) / 256, 256, 0, stream>>>(w2, w2T, 256, 384);
    transpose_w_kernel<<<(512 * 768 + 255) / 256, 256, 0, stream>>>(w3, w3T, 512, 768);

    // city embed
    city_kernel<<<BB, DDIM, 0, stream>>>(stat, W_city, b_city, cv);

    // conv stack
    {
        dim3 grid((2044 + 15) / 16, BB);
        conv_pool_kernel<4, 128, 16, false><<<grid, 128, 0, stream>>>(history, w1T, b1, h1, 2048);
    }
    {
        dim3 grid((2040 + 15) / 16, BB);
        conv_pool_kernel<128, 256, 16, false><<<grid, 256, 0, stream>>>(h1, w2T, b2, h2, 2044);
    }
    {
        dim3 grid((2036 + 15) / 16, BB);
        conv_pool_kernel<256, 512, 16, true><<<grid, 512, 0, stream>>>(h2, w3T, b3, h3, 2040);
    }

    // fused epilogue: 65152 rows / 16 per block = 4072 blocks
    epilogue_kernel<<<(SEQ * BB) / 16, 256, 0, stream>>>(
        input, W_feat, b_feat, h3, cv, g1, beta1, g2, beta2, out);
}

// Round 2
// 595.675 us; speedup vs baseline: 2.6783x; 2.6783x over previous
//
#include <hip/hip_runtime.h>
#include <hip/hip_bf16.h>

#define SEQ 2036
#define BB 32
#define DDIM 512

typedef __attribute__((ext_vector_type(4))) float f32x4;
typedef __attribute__((ext_vector_type(8))) short bf16x8v;
typedef __attribute__((ext_vector_type(8))) unsigned short u16x8;

__device__ __forceinline__ float leaky_f(float x) { return x > 0.f ? x : 0.2f * x; }
__device__ __forceinline__ unsigned short f2bf(float x) {
    unsigned u = __float_as_uint(x);
    return (unsigned short)((u + 0x7fffu + ((u >> 16) & 1u)) >> 16);
}
__device__ __forceinline__ float bf2f(unsigned short h) { return __uint_as_float(((unsigned)h) << 16); }

#define GLOAD_LDS16(g, l)                                                                  \
    __builtin_amdgcn_global_load_lds((__attribute__((address_space(1))) const unsigned int*)(g), \
                                     (__attribute__((address_space(3))) unsigned int*)(l), 16, 0, 0)

// ---- w1 transpose: w[128][12] -> wT[12][128] (fp32, conv1 only) ----
__global__ void transpose_w_kernel(const float* __restrict__ w, float* __restrict__ wT,
                                   int Dout, int K3) {
    int i = blockIdx.x * blockDim.x + threadIdx.x;
    if (i < Dout * K3) {
        int d = i / K3, k = i - d * K3;
        wT[k * Dout + d] = w[i];
    }
}

// ---- weight prep for MFMA convs: build swizzled LDS-image tiles ----
// tile t = (k*NQ + q)*NB + nb : [128 n][32 kk] bf16 with kk-chunk XOR swizzle
__global__ void prep_w_kernel(const float* __restrict__ w, __hip_bfloat16* __restrict__ wp,
                              int CIN, int NB) {
    int idx = blockIdx.x * 256 + threadIdx.x;
    int NQ = CIN >> 5;
    int total = 3 * NQ * NB * 4096;
    if (idx >= total) return;
    int o = idx & 4095, tile = idx >> 12;
    int nb = tile % NB;
    int tmp = tile / NB;
    int q = tmp % NQ, k = tmp / NQ;
    int n = o >> 5, low = o & 31;
    int cs = low >> 3, j = low & 7;
    int c = cs ^ ((n >> 1) & 3);
    int kk = (c << 3) | j;
    float v = w[((size_t)(nb * 128 + n)) * CIN * 3 + (q * 32 + kk) * 3 + k];
    ((unsigned short*)wp)[idx] = f2bf(v);
}

// ---- city embed ----
__global__ void city_kernel(const float* __restrict__ st, const float* __restrict__ Wc,
                            const float* __restrict__ bc, float* __restrict__ c) {
    int b = blockIdx.x, d = threadIdx.x;
    const float* sb = st + b * 100;
    float acc = bc[d];
#pragma unroll 4
    for (int f = 0; f < 100; ++f) acc = fmaf(sb[f], Wc[d * 100 + f], acc);
    c[b * DDIM + d] = acc;
}

// ---- conv1: CIN=4 -> 128, fused pool, writes channels-last bf16 [B][2044][128] ----
__global__ __launch_bounds__(128) void conv1_kernel(const float* __restrict__ in,
                                                    const float* __restrict__ wT,
                                                    const float* __restrict__ bias,
                                                    __hip_bfloat16* __restrict__ out) {
    const int b = blockIdx.y, s0 = blockIdx.x * 32, d = threadIdx.x;
    __shared__ float tile[4][36];
    const float* inb = in + (size_t)b * 4 * 2048;
    for (int i = threadIdx.x; i < 4 * 36; i += 128) {
        int cin = i / 36, p = i - cin * 36;
        int s = s0 + p;
        tile[cin][p] = (s < 2048) ? inb[cin * 2048 + s] : 0.f;
    }
    __syncthreads();
    float acc[34];
#pragma unroll
    for (int i = 0; i < 34; ++i) acc[i] = 0.f;
#pragma unroll
    for (int cin = 0; cin < 4; ++cin) {
        float w0 = wT[(cin * 3 + 0) * 128 + d];
        float w1 = wT[(cin * 3 + 1) * 128 + d];
        float w2 = wT[(cin * 3 + 2) * 128 + d];
        float r0 = tile[cin][0], r1 = tile[cin][1];
#pragma unroll
        for (int p = 0; p < 34; ++p) {
            float r2 = tile[cin][p + 2];
            acc[p] = fmaf(r0, w0, fmaf(r1, w1, fmaf(r2, w2, acc[p])));
            r0 = r1; r1 = r2;
        }
    }
    float bvv = bias[d];
    unsigned short* o16 = (unsigned short*)out;
#pragma unroll
    for (int i = 0; i < 32; ++i) {
        int sp = s0 + i;
        if (sp < 2044) {
            float v = leaky_f(fmaxf(fmaxf(acc[i], acc[i + 1]), acc[i + 2]) + bvv);
            o16[((size_t)b * 2044 + sp) * 128 + d] = f2bf(v);
        }
    }
}

// ---- MFMA conv: channels-last bf16 implicit GEMM, fused bias+leaky+maxpool3 ----
// Block: 256 thr (4 waves, 2x2 wave grid, 64x64/wave), tile 128 conv rows x 128 douts,
// emits 126 pooled rows (M-blocks stride 126). A-panel staged per 128-cin half.
template <int CIN, int DOUT>
__global__ __launch_bounds__(256, 3) void conv_mfma_kernel(
    const __hip_bfloat16* __restrict__ hin,   // [B][Lin][CIN]
    const __hip_bfloat16* __restrict__ wprep, // swizzled tiles
    const float* __restrict__ bias,
    __hip_bfloat16* __restrict__ hout,
    int Lin, int Lpool, long bstride, long sstride)
{
    constexpr int NQ = CIN / 32;
    constexpr int HALVES = (CIN + 127) / 128;
    constexpr int NSTEP = 3 * NQ;
    constexpr int SPH = NSTEP / HALVES;   // steps per half = 12

    __shared__ __attribute__((aligned(16))) unsigned char smem[34816 + 16384];
    unsigned char* panel = smem;            // [130 r][128 cin] bf16, swizzled chunks (33280 B)
    unsigned char* cstage = smem;           // [128 n][136 s] bf16 (34816 B) — reuses panel
    unsigned char* bls = smem + 34816;      // 2 x [128 n][32 kk] bf16 (8192 B each)

    const int t = threadIdx.x;
    const int lane = t & 63, w = t >> 6;
    const int wr = w >> 1, wn = w & 1;
    const int l15 = lane & 15, lg = lane >> 4;
    const int nb = blockIdx.y, b = blockIdx.z;
    const int s0 = blockIdx.x * 126;

    auto stage_panel = [&](int half) {
        const short* src = (const short*)hin + ((size_t)b * Lin) * CIN + half * 128;
        for (int i = t; i < 130 * 16; i += 256) {
            int r = i >> 4, c = i & 15;
            int srow = s0 + r;
            bf16x8v v = {};
            if (srow < Lin) v = *(const bf16x8v*)(src + (size_t)srow * CIN + (c << 3));
            int csw = (c & 8) | ((c ^ r) & 7);
            *(bf16x8v*)(panel + r * 256 + (csw << 4)) = v;
        }
    };
    auto stage_b = [&](int ss, int bi) {
        int k = (ss % SPH) >> 2;
        int qg = (ss / SPH) * 4 + (ss & 3);
        int tile = (k * NQ + qg) * (DOUT / 128) + nb;
        const char* src = (const char*)wprep + (size_t)tile * 8192;
        char* dst = (char*)bls + bi * 8192;
        GLOAD_LDS16(src + t * 16, dst + (w << 10));
        GLOAD_LDS16(src + 4096 + t * 16, dst + 4096 + (w << 10));
    };

    f32x4 acc[4][4];
#pragma unroll
    for (int i = 0; i < 4; ++i)
#pragma unroll
        for (int j = 0; j < 4; ++j) acc[i][j] = (f32x4){0.f, 0.f, 0.f, 0.f};

    stage_panel(0);
    stage_b(0, 0);
    __syncthreads();

    int boff[4];
#pragma unroll
    for (int nf = 0; nf < 4; ++nf) {
        int n = wn * 64 + nf * 16 + l15;
        boff[nf] = n * 64 + ((lg ^ ((n >> 1) & 3)) << 4);
    }
    const int rbse = wr * 64 + l15;

    for (int ss = 0; ss < NSTEP; ++ss) {
        const int bi = ss & 1;
        if (ss + 1 < NSTEP) stage_b(ss + 1, bi ^ 1);
        const int k = (ss % SPH) >> 2;
        const int cc = (ss & 3) * 4 + lg;
        bf16x8v a[4], bfr[4];
#pragma unroll
        for (int mf = 0; mf < 4; ++mf) {
            int r = rbse + mf * 16 + k;
            int csw = (cc & 8) | ((cc ^ r) & 7);
            a[mf] = *(const bf16x8v*)(panel + r * 256 + (csw << 4));
        }
#pragma unroll
        for (int nf = 0; nf < 4; ++nf)
            bfr[nf] = *(const bf16x8v*)(bls + bi * 8192 + boff[nf]);
#pragma unroll
        for (int mf = 0; mf < 4; ++mf)
#pragma unroll
            for (int nf = 0; nf < 4; ++nf)
                acc[mf][nf] = __builtin_amdgcn_mfma_f32_16x16x32_bf16(a[mf], bfr[nf], acc[mf][nf], 0, 0, 0);
        __syncthreads();
        if (HALVES == 2 && ss == SPH - 1) {
            stage_panel(1);
            __syncthreads();
        }
    }

    // write acc -> cstage, transposed bf16 [n][136 s]
#pragma unroll
    for (int mf = 0; mf < 4; ++mf) {
        int srow = wr * 64 + mf * 16 + (lg << 2);
#pragma unroll
        for (int nf = 0; nf < 4; ++nf) {
            int n = wn * 64 + nf * 16 + l15;
            f32x4 v = acc[mf][nf];
            unsigned lo = (unsigned)f2bf(v.x) | ((unsigned)f2bf(v.y) << 16);
            unsigned hi = (unsigned)f2bf(v.z) | ((unsigned)f2bf(v.w) << 16);
            *(uint2*)(cstage + (size_t)n * 272 + srow * 2) = make_uint2(lo, hi);
        }
    }
    __syncthreads();

    // pool(3) + bias + leaky + store
    const int n = t & 127, h = t >> 7;
    const float bv = bias[nb * 128 + n];
    const int SP = (Lpool - s0 < 126) ? (Lpool - s0) : 126;
    const int splo = h ? 63 : 0;
    const int sphim = h ? 126 : 63;
    const int sphi = (SP < sphim) ? SP : sphim;
    const int cbg = h ? 7 : 0, ceg = h ? 16 : 9;
    unsigned short* outp = (unsigned short*)hout;
    const size_t obase = (size_t)b * bstride + (size_t)s0 * sstride + nb * 128 + n;
    float p2 = 0.f, p1 = 0.f;
    for (int j = cbg; j < ceg; ++j) {
        u16x8 ch = *(const u16x8*)(cstage + (size_t)n * 272 + (j << 4));
#pragma unroll
        for (int i = 0; i < 8; ++i) {
            float cur = bf2f(ch[i]);
            int sp = j * 8 + i - 2;
            if (sp >= splo && sp < sphi) {
                float v = fmaxf(fmaxf(p2, p1), cur) + bv;
                outp[obase + (size_t)sp * sstride] = f2bf(leaky_f(v));
            }
            p2 = p1; p1 = cur;
        }
    }
}

// ---- fused epilogue: embed GEMM + leaky + add h3(bf16) + LN1 + city scale + LN2 ----
__global__ __launch_bounds__(256) void epilogue_kernel(
    const float* __restrict__ input,   // [S*B][64]
    const float* __restrict__ Wf,      // [512][64]
    const float* __restrict__ bf,      // [512]
    const __hip_bfloat16* __restrict__ h3,  // [S*B][512] bf16
    const float* __restrict__ cvec,    // [B][512]
    const float* __restrict__ g1, const float* __restrict__ be1,
    const float* __restrict__ g2, const float* __restrict__ be2,
    float* __restrict__ outp)          // [S*B][512]
{
    __shared__ float in_lds[16 * 64];
    __shared__ float W_lds[64 * 65];
    __shared__ float x_lds[16 * 512];
    const int t = threadIdx.x;
    const long r0 = (long)blockIdx.x * 16;
    const unsigned short* h3u = (const unsigned short*)h3;

    for (int idx = t; idx < 16 * 64; idx += 256) in_lds[idx] = input[r0 * 64 + idx];

    for (int chunk = 0; chunk < 8; ++chunk) {
        __syncthreads();
        for (int idx = t; idx < 64 * 64; idx += 256) {
            int dl = idx >> 6, f = idx & 63;
            W_lds[dl * 65 + f] = Wf[(chunk * 64 + dl) * 64 + f];
        }
        __syncthreads();
#pragma unroll
        for (int i = 0; i < 4; ++i) {
            int o = t + 256 * i;
            int row = o >> 6, dl = o & 63;
            int d = chunk * 64 + dl;
            float acc = bf[d];
            const float* inr = &in_lds[row * 64];
            const float* wrp = &W_lds[dl * 65];
#pragma unroll
            for (int f = 0; f < 64; ++f) acc = fmaf(inr[f], wrp[f], acc);
            float x = leaky_f(acc);
            x += bf2f(h3u[(r0 + row) * 512 + d]);
            x_lds[row * 512 + d] = x;
        }
    }
    __syncthreads();

    const int wave = t >> 6, lane = t & 63;
    float g1r[8], b1r[8], g2r[8], b2r[8];
#pragma unroll
    for (int j = 0; j < 8; ++j) {
        int d = lane + 64 * j;
        g1r[j] = g1[d]; b1r[j] = be1[d]; g2r[j] = g2[d]; b2r[j] = be2[d];
    }
    for (int rr = 0; rr < 4; ++rr) {
        int row = wave * 4 + rr;
        long r = r0 + row;
        int b = (int)(r & 31);
        float v[8];
        float s = 0.f;
#pragma unroll
        for (int j = 0; j < 8; ++j) { v[j] = x_lds[row * 512 + lane + 64 * j]; s += v[j]; }
#pragma unroll
        for (int off = 32; off; off >>= 1) s += __shfl_xor(s, off);
        float m = s * (1.f / 512.f);
        float vs = 0.f;
#pragma unroll
        for (int j = 0; j < 8; ++j) { float dd = v[j] - m; vs += dd * dd; }
#pragma unroll
        for (int off = 32; off; off >>= 1) vs += __shfl_xor(vs, off);
        float rstd = rsqrtf(vs * (1.f / 512.f) + 1e-5f);
        float z[8]; float s2 = 0.f;
#pragma unroll
        for (int j = 0; j < 8; ++j) {
            int d = lane + 64 * j;
            float y = (v[j] - m) * rstd * g1r[j] + b1r[j];
            z[j] = y * cvec[b * 512 + d];
            s2 += z[j];
        }
#pragma unroll
        for (int off = 32; off; off >>= 1) s2 += __shfl_xor(s2, off);
        float m2 = s2 * (1.f / 512.f);
        float vs2 = 0.f;
#pragma unroll
        for (int j = 0; j < 8; ++j) { float dd = z[j] - m2; vs2 += dd * dd; }
#pragma unroll
        for (int off = 32; off; off >>= 1) vs2 += __shfl_xor(vs2, off);
        float rstd2 = rsqrtf(vs2 * (1.f / 512.f) + 1e-5f);
#pragma unroll
        for (int j = 0; j < 8; ++j) {
            int d = lane + 64 * j;
            outp[r * 512 + d] = (z[j] - m2) * rstd2 * g2r[j] + b2r[j];
        }
    }
}

extern "C" void kernel_launch(void* const* d_in, const int* in_sizes, int n_in,
                              void* d_out, int out_size, void* d_ws, size_t ws_size,
                              hipStream_t stream) {
    const float* input   = (const float*)d_in[0];
    const float* history = (const float*)d_in[1];
    const float* stat    = (const float*)d_in[2];
    const float* W_feat  = (const float*)d_in[3];
    const float* b_feat  = (const float*)d_in[4];
    const float* w1      = (const float*)d_in[5];
    const float* b1      = (const float*)d_in[6];
    const float* w2      = (const float*)d_in[7];
    const float* b2      = (const float*)d_in[8];
    const float* w3      = (const float*)d_in[9];
    const float* b3      = (const float*)d_in[10];
    const float* g1      = (const float*)d_in[11];
    const float* beta1   = (const float*)d_in[12];
    const float* W_city  = (const float*)d_in[13];
    const float* b_city  = (const float*)d_in[14];
    const float* g2      = (const float*)d_in[15];
    const float* beta2   = (const float*)d_in[16];
    float* out = (float*)d_out;

    char* wsb = (char*)d_ws;
    size_t off = 0;
    auto alloc = [&](size_t bytes) {
        void* p = wsb + off;
        off = (off + bytes + 255) & ~(size_t)255;
        return p;
    };
    __hip_bfloat16* h1  = (__hip_bfloat16*)alloc((size_t)BB * 2044 * 128 * 2);
    __hip_bfloat16* h2  = (__hip_bfloat16*)alloc((size_t)BB * 2040 * 256 * 2);
    __hip_bfloat16* h3  = (__hip_bfloat16*)alloc((size_t)SEQ * BB * 512 * 2);
    float*          cv  = (float*)alloc((size_t)BB * DDIM * 4);
    float*          w1T = (float*)alloc(12 * 128 * 4);
    __hip_bfloat16* w2P = (__hip_bfloat16*)alloc((size_t)3 * 4 * 2 * 4096 * 2);
    __hip_bfloat16* w3P = (__hip_bfloat16*)alloc((size_t)3 * 8 * 4 * 4096 * 2);

    transpose_w_kernel<<<(12 * 128 + 255) / 256, 256, 0, stream>>>(w1, w1T, 128, 12);
    prep_w_kernel<<<(3 * 4 * 2 * 4096) / 256, 256, 0, stream>>>(w2, w2P, 128, 2);
    prep_w_kernel<<<(3 * 8 * 4 * 4096) / 256, 256, 0, stream>>>(w3, w3P, 256, 4);
    city_kernel<<<BB, DDIM, 0, stream>>>(stat, W_city, b_city, cv);

    conv1_kernel<<<dim3(64, BB), 128, 0, stream>>>(history, w1T, b1, h1);
    conv_mfma_kernel<128, 256><<<dim3(17, 2, BB), 256, 0, stream>>>(
        h1, w2P, b2, h2, 2044, 2040, 2040L * 256, 256);
    conv_mfma_kernel<256, 512><<<dim3(17, 4, BB), 256, 0, stream>>>(
        h2, w3P, b3, h3, 2040, 2036, 512, 32L * 512);

    epilogue_kernel<<<(SEQ * BB) / 16, 256, 0, stream>>>(
        input, W_feat, b_feat, h3, cv, g1, beta1, g2, beta2, out);
}

// Round 4
// 209.877 us; speedup vs baseline: 7.6016x; 2.8382x over previous
//
#include <hip/hip_runtime.h>
#include <hip/hip_bf16.h>

#define SEQ 2036
#define BB 32
#define DDIM 512

typedef __attribute__((ext_vector_type(4))) float f32x4;
typedef __attribute__((ext_vector_type(8))) short bf16x8v;
typedef __attribute__((ext_vector_type(8))) unsigned short u16x8;

__device__ __forceinline__ float leaky_f(float x) { return x > 0.f ? x : 0.2f * x; }
__device__ __forceinline__ unsigned short f2bf(float x) {
    unsigned u = __float_as_uint(x);
    return (unsigned short)((u + 0x7fffu + ((u >> 16) & 1u)) >> 16);
}
__device__ __forceinline__ float bf2f(unsigned short h) { return __uint_as_float(((unsigned)h) << 16); }

#define GLOAD_LDS16(g, l)                                                                  \
    __builtin_amdgcn_global_load_lds((__attribute__((address_space(1))) const unsigned int*)(g), \
                                     (__attribute__((address_space(3))) unsigned int*)(l), 16, 0, 0)

// ---- w1 transpose: w[128][12] -> wT[12][128] (fp32, conv1 only) ----
__global__ void transpose_w_kernel(const float* __restrict__ w, float* __restrict__ wT,
                                   int Dout, int K3) {
    int i = blockIdx.x * blockDim.x + threadIdx.x;
    if (i < Dout * K3) {
        int d = i / K3, k = i - d * K3;
        wT[k * Dout + d] = w[i];
    }
}

// ---- weight prep for MFMA convs: build swizzled LDS-image tiles ----
__global__ void prep_w_kernel(const float* __restrict__ w, __hip_bfloat16* __restrict__ wp,
                              int CIN, int NB) {
    int idx = blockIdx.x * 256 + threadIdx.x;
    int NQ = CIN >> 5;
    int total = 3 * NQ * NB * 4096;
    if (idx >= total) return;
    int o = idx & 4095, tile = idx >> 12;
    int nb = tile % NB;
    int tmp = tile / NB;
    int q = tmp % NQ, k = tmp / NQ;
    int n = o >> 5, low = o & 31;
    int cs = low >> 3, j = low & 7;
    int c = cs ^ ((n >> 1) & 3);
    int kk = (c << 3) | j;
    float v = w[((size_t)(nb * 128 + n)) * CIN * 3 + (q * 32 + kk) * 3 + k];
    ((unsigned short*)wp)[idx] = f2bf(v);
}

// ---- W_feat prep: per-lane-ordered bf16 B-fragments. frag = q*32+j (64 frags) ----
// flat idx: frag*512 + lane*8 + e ; d = j*16 + (lane&15), f = q*32 + (lane>>4)*8 + e
__global__ void prep_wf_kernel(const float* __restrict__ Wf, __hip_bfloat16* __restrict__ wfP) {
    int idx = blockIdx.x * 256 + threadIdx.x;   // 0..32767
    int e = idx & 7;
    int l = (idx >> 3) & 63;
    int frag = idx >> 9;
    int q = frag >> 5, j = frag & 31;
    int n = l & 15, g = l >> 4;
    ((unsigned short*)wfP)[idx] = f2bf(Wf[(j * 16 + n) * 64 + q * 32 + g * 8 + e]);
}

// ---- city embed ----
__global__ void city_kernel(const float* __restrict__ st, const float* __restrict__ Wc,
                            const float* __restrict__ bc, float* __restrict__ c) {
    int b = blockIdx.x, d = threadIdx.x;
    const float* sb = st + b * 100;
    float acc = bc[d];
#pragma unroll 4
    for (int f = 0; f < 100; ++f) acc = fmaf(sb[f], Wc[d * 100 + f], acc);
    c[b * DDIM + d] = acc;
}

// ---- conv1: CIN=4 -> 128, fused pool, writes channels-last bf16 [B][2044][128] ----
__global__ __launch_bounds__(128) void conv1_kernel(const float* __restrict__ in,
                                                    const float* __restrict__ wT,
                                                    const float* __restrict__ bias,
                                                    __hip_bfloat16* __restrict__ out) {
    const int b = blockIdx.y, s0 = blockIdx.x * 32, d = threadIdx.x;
    __shared__ float tile[4][36];
    const float* inb = in + (size_t)b * 4 * 2048;
    for (int i = threadIdx.x; i < 4 * 36; i += 128) {
        int cin = i / 36, p = i - cin * 36;
        int s = s0 + p;
        tile[cin][p] = (s < 2048) ? inb[cin * 2048 + s] : 0.f;
    }
    __syncthreads();
    float acc[34];
#pragma unroll
    for (int i = 0; i < 34; ++i) acc[i] = 0.f;
#pragma unroll
    for (int cin = 0; cin < 4; ++cin) {
        float w0 = wT[(cin * 3 + 0) * 128 + d];
        float w1 = wT[(cin * 3 + 1) * 128 + d];
        float w2 = wT[(cin * 3 + 2) * 128 + d];
        float r0 = tile[cin][0], r1 = tile[cin][1];
#pragma unroll
        for (int p = 0; p < 34; ++p) {
            float r2 = tile[cin][p + 2];
            acc[p] = fmaf(r0, w0, fmaf(r1, w1, fmaf(r2, w2, acc[p])));
            r0 = r1; r1 = r2;
        }
    }
    float bvv = bias[d];
    unsigned short* o16 = (unsigned short*)out;
#pragma unroll
    for (int i = 0; i < 32; ++i) {
        int sp = s0 + i;
        if (sp < 2044) {
            float v = leaky_f(fmaxf(fmaxf(acc[i], acc[i + 1]), acc[i + 2]) + bvv);
            o16[((size_t)b * 2044 + sp) * 128 + d] = f2bf(v);
        }
    }
}

// ---- MFMA conv: channels-last bf16 implicit GEMM, fused bias+leaky+maxpool3 ----
template <int CIN, int DOUT>
__global__ __launch_bounds__(256, 3) void conv_mfma_kernel(
    const __hip_bfloat16* __restrict__ hin,
    const __hip_bfloat16* __restrict__ wprep,
    const float* __restrict__ bias,
    __hip_bfloat16* __restrict__ hout,
    int Lin, int Lpool, long bstride, long sstride)
{
    constexpr int NQ = CIN / 32;
    constexpr int HALVES = (CIN + 127) / 128;
    constexpr int NSTEP = 3 * NQ;
    constexpr int SPH = NSTEP / HALVES;

    __shared__ __attribute__((aligned(16))) unsigned char smem[34816 + 16384];
    unsigned char* panel = smem;
    unsigned char* cstage = smem;
    unsigned char* bls = smem + 34816;

    const int t = threadIdx.x;
    const int lane = t & 63, w = t >> 6;
    const int wr = w >> 1, wn = w & 1;
    const int l15 = lane & 15, lg = lane >> 4;
    const int nb = blockIdx.y, b = blockIdx.z;
    const int s0 = blockIdx.x * 126;

    auto stage_panel = [&](int half) {
        const short* src = (const short*)hin + ((size_t)b * Lin) * CIN + half * 128;
        for (int i = t; i < 130 * 16; i += 256) {
            int r = i >> 4, c = i & 15;
            int srow = s0 + r;
            bf16x8v v = {};
            if (srow < Lin) v = *(const bf16x8v*)(src + (size_t)srow * CIN + (c << 3));
            int csw = (c & 8) | ((c ^ r) & 7);
            *(bf16x8v*)(panel + r * 256 + (csw << 4)) = v;
        }
    };
    auto stage_b = [&](int ss, int bi) {
        int k = (ss % SPH) >> 2;
        int qg = (ss / SPH) * 4 + (ss & 3);
        int tile = (k * NQ + qg) * (DOUT / 128) + nb;
        const char* src = (const char*)wprep + (size_t)tile * 8192;
        char* dst = (char*)bls + bi * 8192;
        GLOAD_LDS16(src + t * 16, dst + (w << 10));
        GLOAD_LDS16(src + 4096 + t * 16, dst + 4096 + (w << 10));
    };

    f32x4 acc[4][4];
#pragma unroll
    for (int i = 0; i < 4; ++i)
#pragma unroll
        for (int j = 0; j < 4; ++j) acc[i][j] = (f32x4){0.f, 0.f, 0.f, 0.f};

    stage_panel(0);
    stage_b(0, 0);
    __syncthreads();

    int boff[4];
#pragma unroll
    for (int nf = 0; nf < 4; ++nf) {
        int n = wn * 64 + nf * 16 + l15;
        boff[nf] = n * 64 + ((lg ^ ((n >> 1) & 3)) << 4);
    }
    const int rbse = wr * 64 + l15;

    for (int ss = 0; ss < NSTEP; ++ss) {
        const int bi = ss & 1;
        if (ss + 1 < NSTEP) stage_b(ss + 1, bi ^ 1);
        const int k = (ss % SPH) >> 2;
        const int cc = (ss & 3) * 4 + lg;
        bf16x8v a[4], bfr[4];
#pragma unroll
        for (int mf = 0; mf < 4; ++mf) {
            int r = rbse + mf * 16 + k;
            int csw = (cc & 8) | ((cc ^ r) & 7);
            a[mf] = *(const bf16x8v*)(panel + r * 256 + (csw << 4));
        }
#pragma unroll
        for (int nf = 0; nf < 4; ++nf)
            bfr[nf] = *(const bf16x8v*)(bls + bi * 8192 + boff[nf]);
#pragma unroll
        for (int mf = 0; mf < 4; ++mf)
#pragma unroll
            for (int nf = 0; nf < 4; ++nf)
                acc[mf][nf] = __builtin_amdgcn_mfma_f32_16x16x32_bf16(a[mf], bfr[nf], acc[mf][nf], 0, 0, 0);
        __syncthreads();
        if (HALVES == 2 && ss == SPH - 1) {
            stage_panel(1);
            __syncthreads();
        }
    }

#pragma unroll
    for (int mf = 0; mf < 4; ++mf) {
        int srow = wr * 64 + mf * 16 + (lg << 2);
#pragma unroll
        for (int nf = 0; nf < 4; ++nf) {
            int n = wn * 64 + nf * 16 + l15;
            f32x4 v = acc[mf][nf];
            unsigned lo = (unsigned)f2bf(v.x) | ((unsigned)f2bf(v.y) << 16);
            unsigned hi = (unsigned)f2bf(v.z) | ((unsigned)f2bf(v.w) << 16);
            *(uint2*)(cstage + (size_t)n * 272 + srow * 2) = make_uint2(lo, hi);
        }
    }
    __syncthreads();

    const int n = t & 127, h = t >> 7;
    const float bv = bias[nb * 128 + n];
    const int SP = (Lpool - s0 < 126) ? (Lpool - s0) : 126;
    const int splo = h ? 63 : 0;
    const int sphim = h ? 126 : 63;
    const int sphi = (SP < sphim) ? SP : sphim;
    const int cbg = h ? 7 : 0, ceg = h ? 16 : 9;
    unsigned short* outp = (unsigned short*)hout;
    const size_t obase = (size_t)b * bstride + (size_t)s0 * sstride + nb * 128 + n;
    float p2 = 0.f, p1 = 0.f;
    for (int j = cbg; j < ceg; ++j) {
        u16x8 ch = *(const u16x8*)(cstage + (size_t)n * 272 + (j << 4));
#pragma unroll
        for (int i = 0; i < 8; ++i) {
            float cur = bf2f(ch[i]);
            int sp = j * 8 + i - 2;
            if (sp >= splo && sp < sphi) {
                float v = fmaxf(fmaxf(p2, p1), cur) + bv;
                outp[obase + (size_t)sp * sstride] = f2bf(leaky_f(v));
            }
            p2 = p1; p1 = cur;
        }
    }
}

// ---- epilogue v2: MFMA embed GEMM -> x_lds, then round-2-verified LN section ----
// Block = 256 thr (4 waves), 16 rows. Wave w computes cols w*128..w*128+127.
__global__ __launch_bounds__(256) void epi_mfma2_kernel(
    const float* __restrict__ input,        // [R][64] fp32
    const __hip_bfloat16* __restrict__ wfP, // packed B frags
    const float* __restrict__ bfeat,        // [512]
    const __hip_bfloat16* __restrict__ h3,  // [R][512] bf16
    const float* __restrict__ cvec,         // [32][512]
    const float* __restrict__ g1, const float* __restrict__ be1,
    const float* __restrict__ g2, const float* __restrict__ be2,
    float* __restrict__ outp)               // [R][512]
{
    __shared__ float x_lds[16 * 512];
    const int t = threadIdx.x;
    const int lane = t & 63, w = t >> 6;
    const int l15 = lane & 15, lg = lane >> 4;
    const long r0 = (long)blockIdx.x * 16;

    // --- MFMA embed GEMM: D rows = lg*4+i, cols d = (w*8+jl)*16 + l15 ---
    f32x4 acc[8];
#pragma unroll
    for (int jl = 0; jl < 8; ++jl) acc[jl] = (f32x4){0.f, 0.f, 0.f, 0.f};

    const unsigned short* wp = (const unsigned short*)wfP;
#pragma unroll
    for (int q = 0; q < 2; ++q) {
        const float* ap = input + (r0 + l15) * 64 + q * 32 + lg * 8;
        f32x4 a0 = *(const f32x4*)ap;
        f32x4 a1 = *(const f32x4*)(ap + 4);
        bf16x8v af;
        af[0] = (short)f2bf(a0.x); af[1] = (short)f2bf(a0.y);
        af[2] = (short)f2bf(a0.z); af[3] = (short)f2bf(a0.w);
        af[4] = (short)f2bf(a1.x); af[5] = (short)f2bf(a1.y);
        af[6] = (short)f2bf(a1.z); af[7] = (short)f2bf(a1.w);
#pragma unroll
        for (int jl = 0; jl < 8; ++jl) {
            int frag = q * 32 + w * 8 + jl;
            bf16x8v bfr = *(const bf16x8v*)(wp + ((size_t)frag * 64 + lane) * 8);
            acc[jl] = __builtin_amdgcn_mfma_f32_16x16x32_bf16(af, bfr, acc[jl], 0, 0, 0);
        }
    }

    // bias + leaky + h3 add -> x_lds
    const unsigned short* h3u = (const unsigned short*)h3;
#pragma unroll
    for (int jl = 0; jl < 8; ++jl) {
        int d = (w * 8 + jl) * 16 + l15;
        float bfv = bfeat[d];
#pragma unroll
        for (int i = 0; i < 4; ++i) {
            int row = lg * 4 + i;
            float x = leaky_f(acc[jl][i] + bfv) + bf2f(h3u[(r0 + row) * 512 + d]);
            x_lds[row * 512 + d] = x;
        }
    }
    __syncthreads();

    // --- round-2-verified LN1 + city + LN2 section (verbatim) ---
    float g1r[8], b1r[8], g2r[8], b2r[8];
#pragma unroll
    for (int j = 0; j < 8; ++j) {
        int d = lane + 64 * j;
        g1r[j] = g1[d]; b1r[j] = be1[d]; g2r[j] = g2[d]; b2r[j] = be2[d];
    }
    for (int rr = 0; rr < 4; ++rr) {
        int row = w * 4 + rr;
        long r = r0 + row;
        int b = (int)(r & 31);
        float v[8];
        float s = 0.f;
#pragma unroll
        for (int j = 0; j < 8; ++j) { v[j] = x_lds[row * 512 + lane + 64 * j]; s += v[j]; }
#pragma unroll
        for (int off = 32; off; off >>= 1) s += __shfl_xor(s, off);
        float m = s * (1.f / 512.f);
        float vs = 0.f;
#pragma unroll
        for (int j = 0; j < 8; ++j) { float dd = v[j] - m; vs += dd * dd; }
#pragma unroll
        for (int off = 32; off; off >>= 1) vs += __shfl_xor(vs, off);
        float rstd = rsqrtf(vs * (1.f / 512.f) + 1e-5f);
        float z[8]; float s2 = 0.f;
#pragma unroll
        for (int j = 0; j < 8; ++j) {
            int d = lane + 64 * j;
            float y = (v[j] - m) * rstd * g1r[j] + b1r[j];
            z[j] = y * cvec[b * 512 + d];
            s2 += z[j];
        }
#pragma unroll
        for (int off = 32; off; off >>= 1) s2 += __shfl_xor(s2, off);
        float m2 = s2 * (1.f / 512.f);
        float vs2 = 0.f;
#pragma unroll
        for (int j = 0; j < 8; ++j) { float dd = z[j] - m2; vs2 += dd * dd; }
#pragma unroll
        for (int off = 32; off; off >>= 1) vs2 += __shfl_xor(vs2, off);
        float rstd2 = rsqrtf(vs2 * (1.f / 512.f) + 1e-5f);
#pragma unroll
        for (int j = 0; j < 8; ++j) {
            int d = lane + 64 * j;
            outp[r * 512 + d] = (z[j] - m2) * rstd2 * g2r[j] + b2r[j];
        }
    }
}

extern "C" void kernel_launch(void* const* d_in, const int* in_sizes, int n_in,
                              void* d_out, int out_size, void* d_ws, size_t ws_size,
                              hipStream_t stream) {
    const float* input   = (const float*)d_in[0];
    const float* history = (const float*)d_in[1];
    const float* stat    = (const float*)d_in[2];
    const float* W_feat  = (const float*)d_in[3];
    const float* b_feat  = (const float*)d_in[4];
    const float* w1      = (const float*)d_in[5];
    const float* b1      = (const float*)d_in[6];
    const float* w2      = (const float*)d_in[7];
    const float* b2      = (const float*)d_in[8];
    const float* w3      = (const float*)d_in[9];
    const float* b3      = (const float*)d_in[10];
    const float* g1      = (const float*)d_in[11];
    const float* beta1   = (const float*)d_in[12];
    const float* W_city  = (const float*)d_in[13];
    const float* b_city  = (const float*)d_in[14];
    const float* g2      = (const float*)d_in[15];
    const float* beta2   = (const float*)d_in[16];
    float* out = (float*)d_out;

    char* wsb = (char*)d_ws;
    size_t off = 0;
    auto alloc = [&](size_t bytes) {
        void* p = wsb + off;
        off = (off + bytes + 255) & ~(size_t)255;
        return p;
    };
    __hip_bfloat16* h1  = (__hip_bfloat16*)alloc((size_t)BB * 2044 * 128 * 2);
    __hip_bfloat16* h2  = (__hip_bfloat16*)alloc((size_t)BB * 2040 * 256 * 2);
    __hip_bfloat16* h3  = (__hip_bfloat16*)alloc((size_t)SEQ * BB * 512 * 2);
    float*          cv  = (float*)alloc((size_t)BB * DDIM * 4);
    float*          w1T = (float*)alloc(12 * 128 * 4);
    __hip_bfloat16* w2P = (__hip_bfloat16*)alloc((size_t)3 * 4 * 2 * 4096 * 2);
    __hip_bfloat16* w3P = (__hip_bfloat16*)alloc((size_t)3 * 8 * 4 * 4096 * 2);
    __hip_bfloat16* wfP = (__hip_bfloat16*)alloc((size_t)64 * 512 * 2);

    transpose_w_kernel<<<(12 * 128 + 255) / 256, 256, 0, stream>>>(w1, w1T, 128, 12);
    prep_w_kernel<<<(3 * 4 * 2 * 4096) / 256, 256, 0, stream>>>(w2, w2P, 128, 2);
    prep_w_kernel<<<(3 * 8 * 4 * 4096) / 256, 256, 0, stream>>>(w3, w3P, 256, 4);
    prep_wf_kernel<<<(64 * 512) / 256, 256, 0, stream>>>(W_feat, wfP);
    city_kernel<<<BB, DDIM, 0, stream>>>(stat, W_city, b_city, cv);

    conv1_kernel<<<dim3(64, BB), 128, 0, stream>>>(history, w1T, b1, h1);
    conv_mfma_kernel<128, 256><<<dim3(17, 2, BB), 256, 0, stream>>>(
        h1, w2P, b2, h2, 2044, 2040, 2040L * 256, 256);
    conv_mfma_kernel<256, 512><<<dim3(17, 4, BB), 256, 0, stream>>>(
        h2, w3P, b3, h3, 2040, 2036, 512, 32L * 512);

    epi_mfma2_kernel<<<(SEQ * BB) / 16, 256, 0, stream>>>(
        input, wfP, b_feat, h3, cv, g1, beta1, g2, beta2, out);
}